// Round 7
// baseline (106.788 us; speedup 1.0000x reference)
//
#include <hip/hip_runtime.h>
#include <hip/hip_bf16.h>

#define IN_F 256
#define OU_F 64
#define BKN 64           // nodes per bucket
#define BSHIFT 6
#define NBMAX 1024       // max buckets supported by fused path
#define CHUNK 4096       // edges per partition block
#define CAP 4096         // max records staged in LDS by csr_gather

typedef __attribute__((ext_vector_type(8))) short short8;
typedef __attribute__((ext_vector_type(4))) float f32x4;

// ---------------- GEMM: hp(bf16) = h @ W via bf16 MFMA ----------------
// W in LDS transposed (stride 264 -> 2-lane/bank, free). h tile staged bf16
// in LDS, XOR-swizzled. Block 0 also zeroes bcnt[0..NBMAX] (incl. the
// done-ticket slot) for the downstream hist_scan -- saves a memset dispatch.
__global__ void __launch_bounds__(256)
gemm_mfma_kernel(const float* __restrict__ h, const float* __restrict__ W,
                 __hip_bfloat16* __restrict__ hp, int* __restrict__ bcnt, int N)
{
    __shared__ unsigned short Wt[64][264];   // 33792 B
    __shared__ uint4 hsv[2048];              // 32768 B, 64 rows x 512 B swizzled
    unsigned char* hs = reinterpret_cast<unsigned char*>(hsv);
    const int t = threadIdx.x;

    if (blockIdx.x == 0)
        for (int i = t; i <= NBMAX; i += 256) bcnt[i] = 0;

#pragma unroll
    for (int i = 0; i < 32; ++i) {
        int p  = t + i * 256;
        int c  = p & 63;
        int k0 = (p >> 6) << 1;
        float x = W[(size_t)k0 * OU_F + c];
        float y = W[(size_t)(k0 + 1) * OU_F + c];
        __hip_bfloat162 bb = __float22bfloat162_rn(make_float2(x, y));
        *reinterpret_cast<unsigned*>(&Wt[c][k0]) = *reinterpret_cast<unsigned*>(&bb);
    }

    const int rbase = blockIdx.x * 64;
    const int nrow  = min(64, N - rbase);
#pragma unroll
    for (int i = 0; i < 16; ++i) {
        int idx = t + i * 256;
        int r  = idx >> 6;
        int k4 = idx & 63;
        float4 v = make_float4(0.f, 0.f, 0.f, 0.f);
        if (r < nrow)
            v = reinterpret_cast<const float4*>(h)[(size_t)(rbase + r) * (IN_F / 4) + k4];
        __hip_bfloat162 lo = __float22bfloat162_rn(make_float2(v.x, v.y));
        __hip_bfloat162 hi = __float22bfloat162_rn(make_float2(v.z, v.w));
        unsigned boff = (unsigned)r * 512u + (((unsigned)k4 * 8u) ^ (((unsigned)r & 7u) << 4));
        uint2 pk;
        pk.x = *reinterpret_cast<unsigned*>(&lo);
        pk.y = *reinterpret_cast<unsigned*>(&hi);
        *reinterpret_cast<uint2*>(&hs[boff]) = pk;
    }
    __syncthreads();

    const int l    = t & 63;
    const int wv   = t >> 6;
    const int cl   = l & 15;
    const int kg   = l >> 4;
    const int rloc = wv * 16 + cl;

    f32x4 acc[4];
#pragma unroll
    for (int nt = 0; nt < 4; ++nt) acc[nt] = (f32x4){0.f, 0.f, 0.f, 0.f};

#pragma unroll
    for (int ks = 0; ks < 8; ++ks) {
        unsigned aoff = (unsigned)rloc * 512u +
                        (((unsigned)(ks * 64 + kg * 16)) ^ (((unsigned)rloc & 7u) << 4));
        short8 af = *reinterpret_cast<const short8*>(&hs[aoff]);
#pragma unroll
        for (int nt = 0; nt < 4; ++nt) {
            short8 bf = *reinterpret_cast<const short8*>(&Wt[nt * 16 + cl][ks * 32 + kg * 8]);
            acc[nt] = __builtin_amdgcn_mfma_f32_16x16x32_bf16(af, bf, acc[nt], 0, 0, 0);
        }
    }

#pragma unroll
    for (int nt = 0; nt < 4; ++nt)
#pragma unroll
        for (int rg = 0; rg < 4; ++rg) {
            int rr = rbase + wv * 16 + kg * 4 + rg;
            if (rr < N)
                hp[(size_t)rr * OU_F + nt * 16 + cl] = __float2bfloat16(acc[nt][rg]);
        }
}

// ---------------- hist + scan fused (last-block-done ticket) ----------------
__global__ void __launch_bounds__(256)
hist_scan_kernel(const int* __restrict__ col, int* __restrict__ bcnt,
                 int* __restrict__ boffs, int* __restrict__ bcursor, int E, int NB)
{
    __shared__ int lh[NBMAX];
    __shared__ int s[256];
    __shared__ int isLast;
    const int t = threadIdx.x;

    for (int i = t; i < NB; i += 256) lh[i] = 0;
    __syncthreads();

    const int n4 = E >> 2;
    const int4* c4 = (const int4*)col;
    for (int i = blockIdx.x * 256 + t; i < n4; i += gridDim.x * 256) {
        int4 v = c4[i];
        atomicAdd(&lh[v.x >> BSHIFT], 1);
        atomicAdd(&lh[v.y >> BSHIFT], 1);
        atomicAdd(&lh[v.z >> BSHIFT], 1);
        atomicAdd(&lh[v.w >> BSHIFT], 1);
    }
    if (blockIdx.x == 0)
        for (int e = (n4 << 2) + t; e < E; e += 256)
            atomicAdd(&lh[col[e] >> BSHIFT], 1);
    __syncthreads();

    for (int i = t; i < NB; i += 256)
        if (lh[i]) atomicAdd(&bcnt[i], lh[i]);

    __threadfence();
    if (t == 0) {
        int v = atomicAdd(&bcnt[NBMAX], 1);
        isLast = (v == (int)gridDim.x - 1);
    }
    __syncthreads();
    if (!isLast) return;

    // last block: exclusive scan of bcnt[0..NB-1]
    for (int i = t; i < NB; i += 256)
        lh[i] = __hip_atomic_load(&bcnt[i], __ATOMIC_RELAXED, __HIP_MEMORY_SCOPE_AGENT);
    __syncthreads();

    int idx = t * 4;
    int c0 = (idx     < NB) ? lh[idx]     : 0;
    int c1 = (idx + 1 < NB) ? lh[idx + 1] : 0;
    int c2 = (idx + 2 < NB) ? lh[idx + 2] : 0;
    int c3 = (idx + 3 < NB) ? lh[idx + 3] : 0;
    int s0 = c0, s1 = s0 + c1, s2 = s1 + c2, s3 = s2 + c3;
    s[t] = s3;
    __syncthreads();
    for (int d = 1; d < 256; d <<= 1) {
        int v = (t >= d) ? s[t - d] : 0;
        __syncthreads();
        s[t] += v;
        __syncthreads();
    }
    int excl = (t > 0) ? s[t - 1] : 0;
    if (idx     < NB) { boffs[idx]     = excl;      bcursor[idx]     = excl;      }
    if (idx + 1 < NB) { boffs[idx + 1] = excl + s0; bcursor[idx + 1] = excl + s0; }
    if (idx + 2 < NB) { boffs[idx + 2] = excl + s1; bcursor[idx + 2] = excl + s1; }
    if (idx + 3 < NB) { boffs[idx + 3] = excl + s2; bcursor[idx + 3] = excl + s2; }
    if (t == 255) boffs[NB] = s[255];
}

// ---------------- partition: counting-sort edges into buckets ----------------
__global__ void __launch_bounds__(256)
partition_kernel(const int* __restrict__ row, const int* __restrict__ col,
                 const float* __restrict__ vals, int* __restrict__ bcursor,
                 int2* __restrict__ epk, int E, int NB)
{
    __shared__ int  hist[NBMAX];
    __shared__ int  X[NBMAX];
    __shared__ int  gshift[NBMAX];
    __shared__ int  s[256];
    __shared__ int2 stage[CHUNK];  // 32 KB
    __shared__ int  gpos[CHUNK];   // 16 KB

    const int t = threadIdx.x;
    const int base = blockIdx.x * CHUNK;
    const int n = min(CHUNK, E - base);

    for (int i = t; i < NBMAX; i += 256) hist[i] = 0;
    __syncthreads();

#pragma unroll
    for (int k = 0; k < CHUNK / 256; ++k) {
        int i = t + k * 256;
        if (i < n) atomicAdd(&hist[col[base + i] >> BSHIFT], 1);
    }
    __syncthreads();

    int idx = t * 4;
    int c0 = hist[idx], c1 = hist[idx + 1], c2 = hist[idx + 2], c3 = hist[idx + 3];
    int s0 = c0, s1 = s0 + c1, s2 = s1 + c2, s3 = s2 + c3;
    s[t] = s3;
    __syncthreads();
    for (int d = 1; d < 256; d <<= 1) {
        int v = (t >= d) ? s[t - d] : 0;
        __syncthreads();
        s[t] += v;
        __syncthreads();
    }
    int excl = (t > 0) ? s[t - 1] : 0;
    X[idx]     = excl;
    X[idx + 1] = excl + s0;
    X[idx + 2] = excl + s1;
    X[idx + 3] = excl + s2;
    __syncthreads();

    for (int i = t; i < NB; i += 256) {
        int hcnt = hist[i];
        int g = hcnt ? atomicAdd(&bcursor[i], hcnt) : 0;
        gshift[i] = g - X[i];
    }
    __syncthreads();

#pragma unroll
    for (int k = 0; k < CHUNK / 256; ++k) {
        int i = t + k * 256;
        if (i < n) {
            int e  = base + i;
            int cv = col[e];
            int b  = cv >> BSHIFT;
            int r  = atomicAdd(&X[b], 1);
            unsigned pk = (unsigned)row[e] | ((unsigned)(cv & (BKN - 1)) << 17);
            stage[r] = make_int2((int)pk, __float_as_int(vals[e]));
            gpos[r]  = gshift[b] + r;
        }
    }
    __syncthreads();

#pragma unroll
    for (int k = 0; k < CHUNK / 256; ++k) {
        int i = t + k * 256;
        if (i < n) epk[gpos[i]] = stage[i];
    }
}

// ---------------- fused within-bucket sort + gather (one block per bucket) ----------------
__global__ void __launch_bounds__(256)
csr_gather_kernel(const __hip_bfloat16* __restrict__ hp, const int* __restrict__ boffs,
                  const int2* __restrict__ epk, float* __restrict__ out, int N)
{
    __shared__ int  cnt[BKN];
    __shared__ int  cur[BKN];
    __shared__ int  noff[BKN + 1];
    __shared__ int2 stage[CAP];    // 32 KB
    const int t = threadIdx.x;
    const int b = blockIdx.x;
    const int s = boffs[b], e = boffs[b + 1];
    const int n = e - s;
    const int node0 = b << BSHIFT;
    const int lane = t & 63;
    const int wv   = t >> 6;

    if (n <= CAP) {
        if (t < BKN) cnt[t] = 0;
        __syncthreads();
        for (int i = t; i < n; i += 256)
            atomicAdd(&cnt[((unsigned)epk[s + i].x) >> 17], 1);
        __syncthreads();
        if (t < 64) {                       // one full wave: shfl scan
            int v = cnt[t], orig = v;
            for (int d = 1; d < 64; d <<= 1) {
                int u = __shfl_up(v, d);
                if (t >= d) v += u;
            }
            noff[t] = v - orig;
            cur[t]  = v - orig;
            if (t == 63) noff[64] = v;
        }
        __syncthreads();
        for (int i = t; i < n; i += 256) {
            int2 r = epk[s + i];
            int pos = atomicAdd(&cur[((unsigned)r.x) >> 17], 1);
            stage[pos] = r;
        }
        __syncthreads();

        for (int nd = wv; nd < BKN; nd += 4) {
            int node = node0 + nd;
            if (node >= N) break;
            int js = noff[nd], je = noff[nd + 1];
            float acc = 0.f;
            int j = js;
            for (; j + 4 <= je; j += 4) {
                int2 r0 = stage[j],     r1 = stage[j + 1];   // wave-uniform LDS broadcast
                int2 r2 = stage[j + 2], r3 = stage[j + 3];
                float x0 = __bfloat162float(hp[((size_t)(r0.x & 0x1FFFF) << 6) + lane]);
                float x1 = __bfloat162float(hp[((size_t)(r1.x & 0x1FFFF) << 6) + lane]);
                float x2 = __bfloat162float(hp[((size_t)(r2.x & 0x1FFFF) << 6) + lane]);
                float x3 = __bfloat162float(hp[((size_t)(r3.x & 0x1FFFF) << 6) + lane]);
                acc = fmaf(__int_as_float(r0.y), x0, acc);
                acc = fmaf(__int_as_float(r1.y), x1, acc);
                acc = fmaf(__int_as_float(r2.y), x2, acc);
                acc = fmaf(__int_as_float(r3.y), x3, acc);
            }
            for (; j < je; ++j) {
                int2 r = stage[j];
                acc = fmaf(__int_as_float(r.y),
                           __bfloat162float(hp[((size_t)(r.x & 0x1FFFF) << 6) + lane]), acc);
            }
            out[(size_t)node * OU_F + lane] = acc;
        }
    } else {
        // degenerate-skew fallback: never expected with ~uniform cols
        for (int nd = wv; nd < BKN; nd += 4) {
            int node = node0 + nd;
            if (node >= N) break;
            float acc = 0.f;
            for (int j = s; j < e; ++j) {
                int2 r = epk[j];
                if ((int)(((unsigned)r.x) >> 17) == nd)
                    acc = fmaf(__int_as_float(r.y),
                               __bfloat162float(hp[((size_t)(r.x & 0x1FFFF) << 6) + lane]), acc);
            }
            out[(size_t)node * OU_F + lane] = acc;
        }
    }
}

// ---------------- fallback (atomic scatter) ----------------
__global__ void __launch_bounds__(256)
scatter_kernel(const __hip_bfloat16* __restrict__ hp, const int* __restrict__ row,
               const int* __restrict__ col, const float* __restrict__ vals,
               float* __restrict__ out, int E)
{
    unsigned int gid = blockIdx.x * 256u + threadIdx.x;
    int e = (int)(gid >> 6);
    if (e >= E) return;
    int f = (int)(gid & 63u);
    int r = row[e], c = col[e];
    float m = vals[e] * __bfloat162float(hp[(size_t)r * OU_F + f]);
    __hip_atomic_fetch_add(&out[(size_t)c * OU_F + f], m,
                           __ATOMIC_RELAXED, __HIP_MEMORY_SCOPE_AGENT);
}

extern "C" void kernel_launch(void* const* d_in, const int* in_sizes, int n_in,
                              void* d_out, int out_size, void* d_ws, size_t ws_size,
                              hipStream_t stream)
{
    const float* h    = (const float*)d_in[0];
    const float* W    = (const float*)d_in[1];
    const int*   row  = (const int*)d_in[2];
    const int*   col  = (const int*)d_in[3];
    const float* vals = (const float*)d_in[4];
    float*       out  = (float*)d_out;

    const int N = in_sizes[0] / IN_F;
    const int E = in_sizes[2];
    const int NB = (N + BKN - 1) / BKN;

    char*  ws  = (char*)d_ws;
    size_t off = 0;
    auto alloc = [&](size_t bytes) -> char* {
        char* p = ws + off;
        off = (off + bytes + 255) & ~(size_t)255;
        return p;
    };
    __hip_bfloat16* hp = (__hip_bfloat16*)alloc((size_t)N * OU_F * 2);
    int*   bcnt    = (int*)  alloc((size_t)(NBMAX + 1) * 4);   // [NBMAX] = done ticket
    int*   boffs   = (int*)  alloc((size_t)(NBMAX + 1) * 4);
    int*   bcursor = (int*)  alloc((size_t)NBMAX * 4);
    int2*  epk     = (int2*) alloc((size_t)E * 8);
    const bool fits = (off <= ws_size) && (NB <= NBMAX) && (N < 131072);

    const int ntiles = (N + 63) / 64;
    gemm_mfma_kernel<<<ntiles, 256, 0, stream>>>(h, W, hp, bcnt, N);

    if (fits) {
        hist_scan_kernel<<<256, 256, 0, stream>>>(col, bcnt, boffs, bcursor, E, NB);
        partition_kernel<<<(E + CHUNK - 1) / CHUNK, 256, 0, stream>>>(
            row, col, vals, bcursor, epk, E, NB);
        csr_gather_kernel<<<NB, 256, 0, stream>>>(hp, boffs, epk, out, N);
    } else {
        hipMemsetAsync(d_out, 0, (size_t)out_size * sizeof(float), stream);
        unsigned long long total = (unsigned long long)E * 64ull;
        unsigned int sgrid = (unsigned int)((total + 255ull) / 256ull);
        scatter_kernel<<<sgrid, 256, 0, stream>>>(hp, row, col, vals, out, E);
    }
}

// Round 8
// 95.517 us; speedup vs baseline: 1.1180x; 1.1180x over previous
//
#include <hip/hip_runtime.h>
#include <hip/hip_bf16.h>

#define IN_F 256
#define OU_F 64
#define BKN 128          // nodes per bucket
#define BSHIFT 7
#define NBMAX 512        // max buckets supported
#define CHUNK 4096       // edges per partition block
#define STAGE_CAP 4096   // max records staged in LDS by csr_kernel

typedef __attribute__((ext_vector_type(8))) short short8;
typedef __attribute__((ext_vector_type(4))) float f32x4;

// ---------------- GEMM: hp(bf16) = h @ W via bf16 MFMA ----------------
// W in LDS transposed (stride 264 -> 2-lane/bank, free). h tile staged bf16
// in LDS, XOR-swizzled. Block 0 zeroes bcnt[0..NBMAX] (incl. ticket) for the
// downstream hist_scan (stream order makes this safe).
__global__ void __launch_bounds__(256)
gemm_mfma_kernel(const float* __restrict__ h, const float* __restrict__ W,
                 __hip_bfloat16* __restrict__ hp, int* __restrict__ bcnt, int N)
{
    __shared__ unsigned short Wt[64][264];   // 33792 B
    __shared__ uint4 hsv[2048];              // 32768 B, 64 rows x 512 B swizzled
    unsigned char* hs = reinterpret_cast<unsigned char*>(hsv);
    const int t = threadIdx.x;

    if (blockIdx.x == 0)
        for (int i = t; i <= NBMAX; i += 256) bcnt[i] = 0;

#pragma unroll
    for (int i = 0; i < 32; ++i) {
        int p  = t + i * 256;
        int c  = p & 63;
        int k0 = (p >> 6) << 1;
        float x = W[(size_t)k0 * OU_F + c];
        float y = W[(size_t)(k0 + 1) * OU_F + c];
        __hip_bfloat162 bb = __float22bfloat162_rn(make_float2(x, y));
        *reinterpret_cast<unsigned*>(&Wt[c][k0]) = *reinterpret_cast<unsigned*>(&bb);
    }

    const int rbase = blockIdx.x * 64;
    const int nrow  = min(64, N - rbase);
#pragma unroll
    for (int i = 0; i < 16; ++i) {
        int idx = t + i * 256;
        int r  = idx >> 6;
        int k4 = idx & 63;
        float4 v = make_float4(0.f, 0.f, 0.f, 0.f);
        if (r < nrow)
            v = reinterpret_cast<const float4*>(h)[(size_t)(rbase + r) * (IN_F / 4) + k4];
        __hip_bfloat162 lo = __float22bfloat162_rn(make_float2(v.x, v.y));
        __hip_bfloat162 hi = __float22bfloat162_rn(make_float2(v.z, v.w));
        unsigned boff = (unsigned)r * 512u + (((unsigned)k4 * 8u) ^ (((unsigned)r & 7u) << 4));
        uint2 pk;
        pk.x = *reinterpret_cast<unsigned*>(&lo);
        pk.y = *reinterpret_cast<unsigned*>(&hi);
        *reinterpret_cast<uint2*>(&hs[boff]) = pk;
    }
    __syncthreads();

    const int l    = t & 63;
    const int wv   = t >> 6;
    const int cl   = l & 15;
    const int kg   = l >> 4;
    const int rloc = wv * 16 + cl;

    f32x4 acc[4];
#pragma unroll
    for (int nt = 0; nt < 4; ++nt) acc[nt] = (f32x4){0.f, 0.f, 0.f, 0.f};

#pragma unroll
    for (int ks = 0; ks < 8; ++ks) {
        unsigned aoff = (unsigned)rloc * 512u +
                        (((unsigned)(ks * 64 + kg * 16)) ^ (((unsigned)rloc & 7u) << 4));
        short8 af = *reinterpret_cast<const short8*>(&hs[aoff]);
#pragma unroll
        for (int nt = 0; nt < 4; ++nt) {
            short8 bf = *reinterpret_cast<const short8*>(&Wt[nt * 16 + cl][ks * 32 + kg * 8]);
            acc[nt] = __builtin_amdgcn_mfma_f32_16x16x32_bf16(af, bf, acc[nt], 0, 0, 0);
        }
    }

#pragma unroll
    for (int nt = 0; nt < 4; ++nt)
#pragma unroll
        for (int rg = 0; rg < 4; ++rg) {
            int rr = rbase + wv * 16 + kg * 4 + rg;
            if (rr < N)
                hp[(size_t)rr * OU_F + nt * 16 + cl] = __float2bfloat16(acc[nt][rg]);
        }
}

// ---------------- hist + scan fused (last-block-done ticket) ----------------
__global__ void __launch_bounds__(256)
hist_scan_kernel(const int* __restrict__ col, int* __restrict__ bcnt,
                 int* __restrict__ boffs, int* __restrict__ bcursor, int E, int NB)
{
    __shared__ int lh[NBMAX];
    __shared__ int s[256];
    __shared__ int isLast;
    const int t = threadIdx.x;

    for (int i = t; i < NB; i += 256) lh[i] = 0;
    __syncthreads();

    const int n4 = E >> 2;
    const int4* c4 = (const int4*)col;
    for (int i = blockIdx.x * 256 + t; i < n4; i += gridDim.x * 256) {
        int4 v = c4[i];
        atomicAdd(&lh[v.x >> BSHIFT], 1);
        atomicAdd(&lh[v.y >> BSHIFT], 1);
        atomicAdd(&lh[v.z >> BSHIFT], 1);
        atomicAdd(&lh[v.w >> BSHIFT], 1);
    }
    if (blockIdx.x == 0)
        for (int e = (n4 << 2) + t; e < E; e += 256)
            atomicAdd(&lh[col[e] >> BSHIFT], 1);
    __syncthreads();

    for (int i = t; i < NB; i += 256)
        if (lh[i]) atomicAdd(&bcnt[i], lh[i]);

    __threadfence();
    if (t == 0) {
        int v = atomicAdd(&bcnt[NBMAX], 1);
        isLast = (v == (int)gridDim.x - 1);
    }
    __syncthreads();
    if (!isLast) return;

    // last block: exclusive scan of bcnt[0..NB-1]  (NB <= 512, 2 per thread)
    for (int i = t; i < NB; i += 256)
        lh[i] = __hip_atomic_load(&bcnt[i], __ATOMIC_RELAXED, __HIP_MEMORY_SCOPE_AGENT);
    __syncthreads();

    int idx = t * 2;
    int c0 = (idx     < NB) ? lh[idx]     : 0;
    int c1 = (idx + 1 < NB) ? lh[idx + 1] : 0;
    int s0 = c0, s1 = s0 + c1;
    s[t] = s1;
    __syncthreads();
    for (int d = 1; d < 256; d <<= 1) {
        int v = (t >= d) ? s[t - d] : 0;
        __syncthreads();
        s[t] += v;
        __syncthreads();
    }
    int excl = (t > 0) ? s[t - 1] : 0;
    if (idx     < NB) { boffs[idx]     = excl;      bcursor[idx]     = excl;      }
    if (idx + 1 < NB) { boffs[idx + 1] = excl + s0; bcursor[idx + 1] = excl + s0; }
    if (t == 255) boffs[NB] = s[255];
}

// ---------------- partition: counting-sort edges into buckets ----------------
__global__ void __launch_bounds__(256)
partition_kernel(const int* __restrict__ row, const int* __restrict__ col,
                 const float* __restrict__ vals, int* __restrict__ bcursor,
                 int2* __restrict__ epk, int E, int NB)
{
    __shared__ int  hist[NBMAX];
    __shared__ int  X[NBMAX];
    __shared__ int  gshift[NBMAX];
    __shared__ int  s[256];
    __shared__ int2 stage[CHUNK];  // 32 KB
    __shared__ int  gpos[CHUNK];   // 16 KB

    const int t = threadIdx.x;
    const int base = blockIdx.x * CHUNK;
    const int n = min(CHUNK, E - base);

    for (int i = t; i < NBMAX; i += 256) hist[i] = 0;
    __syncthreads();

#pragma unroll
    for (int k = 0; k < CHUNK / 256; ++k) {
        int i = t + k * 256;
        if (i < n) atomicAdd(&hist[col[base + i] >> BSHIFT], 1);
    }
    __syncthreads();

    int idx = t * 2;
    int c0 = hist[idx], c1 = hist[idx + 1];
    int s0 = c0, s1 = s0 + c1;
    s[t] = s1;
    __syncthreads();
    for (int d = 1; d < 256; d <<= 1) {
        int v = (t >= d) ? s[t - d] : 0;
        __syncthreads();
        s[t] += v;
        __syncthreads();
    }
    int excl = (t > 0) ? s[t - 1] : 0;
    X[idx]     = excl;
    X[idx + 1] = excl + s0;
    __syncthreads();

    for (int i = t; i < NB; i += 256) {
        int hcnt = hist[i];
        int g = hcnt ? atomicAdd(&bcursor[i], hcnt) : 0;
        gshift[i] = g - X[i];
    }
    __syncthreads();

#pragma unroll
    for (int k = 0; k < CHUNK / 256; ++k) {
        int i = t + k * 256;
        if (i < n) {
            int e  = base + i;
            int cv = col[e];
            int b  = cv >> BSHIFT;
            int r  = atomicAdd(&X[b], 1);
            unsigned pk = (unsigned)row[e] | ((unsigned)(cv & (BKN - 1)) << 17);
            stage[r] = make_int2((int)pk, __float_as_int(vals[e]));
            gpos[r]  = gshift[b] + r;
        }
    }
    __syncthreads();

#pragma unroll
    for (int k = 0; k < CHUNK / 256; ++k) {
        int i = t + k * 256;
        if (i < n) epk[gpos[i]] = stage[i];   // runs of consecutive addresses
    }
}

// ---------------- within-bucket counting sort by node + CSR offsets ----------------
__global__ void __launch_bounds__(256)
csr_kernel(const int2* __restrict__ epk, const int* __restrict__ boffs,
           int2* __restrict__ epk2, int* __restrict__ node_offs,
           int N, int NB)
{
    __shared__ int  cnt[BKN];
    __shared__ int  sc[BKN];
    __shared__ int  cur[BKN];
    __shared__ int2 stage[STAGE_CAP];   // 32 KB
    const int t = threadIdx.x;
    const int b = blockIdx.x;
    const int s = boffs[b], e = boffs[b + 1];
    const int n = e - s;
    const int node0 = b << BSHIFT;

    if (t < BKN) cnt[t] = 0;
    __syncthreads();
    for (int i = t; i < n; i += 256)
        atomicAdd(&cnt[((unsigned)epk[s + i].x) >> 17], 1);
    __syncthreads();

    if (t < BKN) sc[t] = cnt[t];
    __syncthreads();
    for (int d = 1; d < BKN; d <<= 1) {
        int v = 0;
        if (t < BKN && t >= d) v = sc[t - d];
        __syncthreads();
        if (t < BKN) sc[t] += v;
        __syncthreads();
    }
    if (t < BKN) {
        int excl = sc[t] - cnt[t];
        cur[t] = excl;
        int node = node0 + t;
        if (node < N) node_offs[node] = s + excl;
    }
    if (b == NB - 1 && t == 0) node_offs[N] = e;
    __syncthreads();

    if (n <= STAGE_CAP) {
        for (int i = t; i < n; i += 256) {
            int2 r = epk[s + i];
            int pos = atomicAdd(&cur[((unsigned)r.x) >> 17], 1);
            stage[pos] = r;
        }
        __syncthreads();
        for (int i = t; i < n; i += 256)
            epk2[s + i] = stage[i];           // fully coalesced
    } else {
        for (int i = t; i < n; i += 256) {
            int2 r = epk[s + i];
            int pos = atomicAdd(&cur[((unsigned)r.x) >> 17], 1);
            epk2[s + pos] = r;
        }
    }
}

// ---------------- gather: one wave per destination node, no atomics ----------------
__global__ void __launch_bounds__(256)
gather_kernel(const __hip_bfloat16* __restrict__ hp, const int* __restrict__ node_offs,
              const int2* __restrict__ epk2, float* __restrict__ out, int N)
{
    int wid  = (int)((blockIdx.x * 256u + threadIdx.x) >> 6);   // node id
    int lane = threadIdx.x & 63;                                 // feature id
    if (wid >= N) return;
    int s = node_offs[wid], e = node_offs[wid + 1];
    float acc = 0.f;
    for (int base = s; base < e; base += 64) {
        int n = min(64, e - base);
        int2 m = make_int2(0, 0);
        if (lane < n) m = epk2[base + lane];
        int j = 0;
        for (; j + 4 <= n; j += 4) {
            unsigned r0 = (unsigned)__shfl(m.x, j)     & 0x1FFFFu;
            unsigned r1 = (unsigned)__shfl(m.x, j + 1) & 0x1FFFFu;
            unsigned r2 = (unsigned)__shfl(m.x, j + 2) & 0x1FFFFu;
            unsigned r3 = (unsigned)__shfl(m.x, j + 3) & 0x1FFFFu;
            float v0 = __int_as_float(__shfl(m.y, j));
            float v1 = __int_as_float(__shfl(m.y, j + 1));
            float v2 = __int_as_float(__shfl(m.y, j + 2));
            float v3 = __int_as_float(__shfl(m.y, j + 3));
            float x0 = __bfloat162float(hp[((size_t)r0 << 6) + lane]);
            float x1 = __bfloat162float(hp[((size_t)r1 << 6) + lane]);
            float x2 = __bfloat162float(hp[((size_t)r2 << 6) + lane]);
            float x3 = __bfloat162float(hp[((size_t)r3 << 6) + lane]);
            acc = fmaf(v0, x0, acc);
            acc = fmaf(v1, x1, acc);
            acc = fmaf(v2, x2, acc);
            acc = fmaf(v3, x3, acc);
        }
        for (; j < n; ++j) {
            unsigned r = (unsigned)__shfl(m.x, j) & 0x1FFFFu;
            float    v = __int_as_float(__shfl(m.y, j));
            acc = fmaf(v, __bfloat162float(hp[((size_t)r << 6) + lane]), acc);
        }
    }
    out[(size_t)wid * OU_F + lane] = acc;
}

// ---------------- fallback (atomic scatter) ----------------
__global__ void __launch_bounds__(256)
scatter_kernel(const __hip_bfloat16* __restrict__ hp, const int* __restrict__ row,
               const int* __restrict__ col, const float* __restrict__ vals,
               float* __restrict__ out, int E)
{
    unsigned int gid = blockIdx.x * 256u + threadIdx.x;
    int e = (int)(gid >> 6);
    if (e >= E) return;
    int f = (int)(gid & 63u);
    int r = row[e], c = col[e];
    float m = vals[e] * __bfloat162float(hp[(size_t)r * OU_F + f]);
    __hip_atomic_fetch_add(&out[(size_t)c * OU_F + f], m,
                           __ATOMIC_RELAXED, __HIP_MEMORY_SCOPE_AGENT);
}

extern "C" void kernel_launch(void* const* d_in, const int* in_sizes, int n_in,
                              void* d_out, int out_size, void* d_ws, size_t ws_size,
                              hipStream_t stream)
{
    const float* h    = (const float*)d_in[0];
    const float* W    = (const float*)d_in[1];
    const int*   row  = (const int*)d_in[2];
    const int*   col  = (const int*)d_in[3];
    const float* vals = (const float*)d_in[4];
    float*       out  = (float*)d_out;

    const int N = in_sizes[0] / IN_F;
    const int E = in_sizes[2];
    const int NB = (N + BKN - 1) / BKN;

    char*  ws  = (char*)d_ws;
    size_t off = 0;
    auto alloc = [&](size_t bytes) -> char* {
        char* p = ws + off;
        off = (off + bytes + 255) & ~(size_t)255;
        return p;
    };
    __hip_bfloat16* hp = (__hip_bfloat16*)alloc((size_t)N * OU_F * 2);
    int*   bcnt      = (int*)  alloc((size_t)(NBMAX + 1) * 4);   // [NBMAX] = ticket
    int*   boffs     = (int*)  alloc((size_t)(NBMAX + 1) * 4);
    int*   bcursor   = (int*)  alloc((size_t)NBMAX * 4);
    int*   node_offs = (int*)  alloc((size_t)(N + 1) * 4);
    int2*  epk       = (int2*) alloc((size_t)E * 8);
    int2*  epk2      = (int2*) alloc((size_t)E * 8);
    const bool fits = (off <= ws_size) && (NB <= NBMAX) && (N < 131072);

    const int ntiles = (N + 63) / 64;
    gemm_mfma_kernel<<<ntiles, 256, 0, stream>>>(h, W, hp, bcnt, N);

    if (fits) {
        hist_scan_kernel<<<256, 256, 0, stream>>>(col, bcnt, boffs, bcursor, E, NB);
        partition_kernel<<<(E + CHUNK - 1) / CHUNK, 256, 0, stream>>>(
            row, col, vals, bcursor, epk, E, NB);
        csr_kernel<<<NB, 256, 0, stream>>>(epk, boffs, epk2, node_offs, N, NB);
        gather_kernel<<<(N + 3) / 4, 256, 0, stream>>>(hp, node_offs, epk2, out, N);
    } else {
        hipMemsetAsync(d_out, 0, (size_t)out_size * sizeof(float), stream);
        unsigned long long total = (unsigned long long)E * 64ull;
        unsigned int sgrid = (unsigned int)((total + 255ull) / 256ull);
        scatter_kernel<<<sgrid, 256, 0, stream>>>(hp, row, col, vals, out, E);
    }
}

// Round 9
// 94.501 us; speedup vs baseline: 1.1300x; 1.0108x over previous
//
#include <hip/hip_runtime.h>
#include <hip/hip_bf16.h>

#define IN_F 256
#define OU_F 64
#define BKN 128          // nodes per bucket
#define BSHIFT 7
#define NBMAX 512        // max buckets supported
#define CHUNK 4096       // edges per partition block
#define STAGE_CAP 4096   // max records staged in LDS by csr_kernel

typedef __attribute__((ext_vector_type(8))) short short8;
typedef __attribute__((ext_vector_type(4))) float f32x4;

__device__ inline short8 cvt8(float4 a, float4 b)
{
    union { short8 s8; __hip_bfloat162 h2[4]; } u;
    u.h2[0] = __float22bfloat162_rn(make_float2(a.x, a.y));
    u.h2[1] = __float22bfloat162_rn(make_float2(a.z, a.w));
    u.h2[2] = __float22bfloat162_rn(make_float2(b.x, b.y));
    u.h2[3] = __float22bfloat162_rn(make_float2(b.z, b.w));
    return u.s8;
}

// ---------------- GEMM: hp(bf16) = h @ W, B-frags in registers ----------------
// 512 threads = 8 waves: wave = (rowgrp 0..3) x (colgrp 0..1). W staged once
// to LDS (33 KB) then pulled into 16 register B-frags; main loop has NO LDS,
// NO barriers: 16 global A-loads + cvt + 16 MFMA per tile. 512 persistent
// blocks grid-stride 782 tiles. launch_bounds(512,4) -> VGPR<=128, 4 w/SIMD.
__global__ void __launch_bounds__(512, 4)
gemm_mfma_kernel(const float* __restrict__ h, const float* __restrict__ W,
                 __hip_bfloat16* __restrict__ hp, int* __restrict__ bcnt,
                 int N, int ntiles)
{
    __shared__ unsigned short Wt[64][264];   // 33792 B, [col][k] bf16
    const int t = threadIdx.x;

    if (blockIdx.x == 0)
        for (int i = t; i <= NBMAX; i += 512) bcnt[i] = 0;

    // stage W (256x64 fp32) -> Wt transposed bf16 (coalesced, once per block)
#pragma unroll
    for (int i = 0; i < 16; ++i) {
        int p  = t + i * 512;          // 8192 (col, k-pair) slots
        int c  = p & 63;
        int k0 = (p >> 6) << 1;
        float x = W[(size_t)k0 * OU_F + c];
        float y = W[(size_t)(k0 + 1) * OU_F + c];
        __hip_bfloat162 bb = __float22bfloat162_rn(make_float2(x, y));
        *reinterpret_cast<unsigned*>(&Wt[c][k0]) = *reinterpret_cast<unsigned*>(&bb);
    }
    __syncthreads();

    const int l   = t & 63;
    const int wv  = t >> 6;           // 0..7
    const int cl  = l & 15;
    const int kg  = l >> 4;           // 0..3
    const int rg4 = wv & 3;           // row group within 64-row tile
    const int cg  = wv >> 2;          // col group (32 cols each)

    // B-fragments into registers: bfr[nt2][ks], col = cg*32 + nt2*16 + cl
    short8 bfr[2][8];
#pragma unroll
    for (int nt2 = 0; nt2 < 2; ++nt2)
#pragma unroll
        for (int ks = 0; ks < 8; ++ks)
            bfr[nt2][ks] = *reinterpret_cast<const short8*>(
                &Wt[cg * 32 + nt2 * 16 + cl][ks * 32 + kg * 8]);

    for (int tile = blockIdx.x; tile < ntiles; tile += gridDim.x) {
        const int rbase = tile * 64 + rg4 * 16;
        const int r     = rbase + cl;
        const int rld   = min(r, N - 1);
        const float4* hrow = reinterpret_cast<const float4*>(h) + (size_t)rld * (IN_F / 4);

        f32x4 acc0 = (f32x4){0.f, 0.f, 0.f, 0.f};
        f32x4 acc1 = (f32x4){0.f, 0.f, 0.f, 0.f};
#pragma unroll
        for (int ks = 0; ks < 8; ++ks) {
            float4 a0 = hrow[ks * 8 + kg * 2];
            float4 a1 = hrow[ks * 8 + kg * 2 + 1];
            short8 af = cvt8(a0, a1);
            acc0 = __builtin_amdgcn_mfma_f32_16x16x32_bf16(af, bfr[0][ks], acc0, 0, 0, 0);
            acc1 = __builtin_amdgcn_mfma_f32_16x16x32_bf16(af, bfr[1][ks], acc1, 0, 0, 0);
        }

        // D: col = lane&15 (cl), row = kg*4 + reg within the 16-row subtile
#pragma unroll
        for (int rg = 0; rg < 4; ++rg) {
            int rr = rbase + kg * 4 + rg;
            if (rr < N) {
                size_t base = (size_t)rr * OU_F + cg * 32 + cl;
                hp[base]      = __float2bfloat16(acc0[rg]);
                hp[base + 16] = __float2bfloat16(acc1[rg]);
            }
        }
    }
}

// ---------------- hist + scan fused (last-block-done ticket) ----------------
__global__ void __launch_bounds__(256)
hist_scan_kernel(const int* __restrict__ col, int* __restrict__ bcnt,
                 int* __restrict__ boffs, int* __restrict__ bcursor, int E, int NB)
{
    __shared__ int lh[NBMAX];
    __shared__ int s[256];
    __shared__ int isLast;
    const int t = threadIdx.x;

    for (int i = t; i < NB; i += 256) lh[i] = 0;
    __syncthreads();

    const int n4 = E >> 2;
    const int4* c4 = (const int4*)col;
    for (int i = blockIdx.x * 256 + t; i < n4; i += gridDim.x * 256) {
        int4 v = c4[i];
        atomicAdd(&lh[v.x >> BSHIFT], 1);
        atomicAdd(&lh[v.y >> BSHIFT], 1);
        atomicAdd(&lh[v.z >> BSHIFT], 1);
        atomicAdd(&lh[v.w >> BSHIFT], 1);
    }
    if (blockIdx.x == 0)
        for (int e = (n4 << 2) + t; e < E; e += 256)
            atomicAdd(&lh[col[e] >> BSHIFT], 1);
    __syncthreads();

    for (int i = t; i < NB; i += 256)
        if (lh[i]) atomicAdd(&bcnt[i], lh[i]);

    __threadfence();
    if (t == 0) {
        int v = atomicAdd(&bcnt[NBMAX], 1);
        isLast = (v == (int)gridDim.x - 1);
    }
    __syncthreads();
    if (!isLast) return;

    for (int i = t; i < NB; i += 256)
        lh[i] = __hip_atomic_load(&bcnt[i], __ATOMIC_RELAXED, __HIP_MEMORY_SCOPE_AGENT);
    __syncthreads();

    int idx = t * 2;
    int c0 = (idx     < NB) ? lh[idx]     : 0;
    int c1 = (idx + 1 < NB) ? lh[idx + 1] : 0;
    int s0 = c0, s1 = s0 + c1;
    s[t] = s1;
    __syncthreads();
    for (int d = 1; d < 256; d <<= 1) {
        int v = (t >= d) ? s[t - d] : 0;
        __syncthreads();
        s[t] += v;
        __syncthreads();
    }
    int excl = (t > 0) ? s[t - 1] : 0;
    if (idx     < NB) { boffs[idx]     = excl;      bcursor[idx]     = excl;      }
    if (idx + 1 < NB) { boffs[idx + 1] = excl + s0; bcursor[idx + 1] = excl + s0; }
    if (t == 255) boffs[NB] = s[255];
}

// ---------------- partition: counting-sort edges into buckets ----------------
__global__ void __launch_bounds__(256)
partition_kernel(const int* __restrict__ row, const int* __restrict__ col,
                 const float* __restrict__ vals, int* __restrict__ bcursor,
                 int2* __restrict__ epk, int E, int NB)
{
    __shared__ int  hist[NBMAX];
    __shared__ int  X[NBMAX];
    __shared__ int  gshift[NBMAX];
    __shared__ int  s[256];
    __shared__ int2 stage[CHUNK];  // 32 KB
    __shared__ int  gpos[CHUNK];   // 16 KB

    const int t = threadIdx.x;
    const int base = blockIdx.x * CHUNK;
    const int n = min(CHUNK, E - base);

    for (int i = t; i < NBMAX; i += 256) hist[i] = 0;
    __syncthreads();

#pragma unroll
    for (int k = 0; k < CHUNK / 256; ++k) {
        int i = t + k * 256;
        if (i < n) atomicAdd(&hist[col[base + i] >> BSHIFT], 1);
    }
    __syncthreads();

    int idx = t * 2;
    int c0 = hist[idx], c1 = hist[idx + 1];
    int s0 = c0, s1 = s0 + c1;
    s[t] = s1;
    __syncthreads();
    for (int d = 1; d < 256; d <<= 1) {
        int v = (t >= d) ? s[t - d] : 0;
        __syncthreads();
        s[t] += v;
        __syncthreads();
    }
    int excl = (t > 0) ? s[t - 1] : 0;
    X[idx]     = excl;
    X[idx + 1] = excl + s0;
    __syncthreads();

    for (int i = t; i < NB; i += 256) {
        int hcnt = hist[i];
        int g = hcnt ? atomicAdd(&bcursor[i], hcnt) : 0;
        gshift[i] = g - X[i];
    }
    __syncthreads();

#pragma unroll
    for (int k = 0; k < CHUNK / 256; ++k) {
        int i = t + k * 256;
        if (i < n) {
            int e  = base + i;
            int cv = col[e];
            int b  = cv >> BSHIFT;
            int r  = atomicAdd(&X[b], 1);
            unsigned pk = (unsigned)row[e] | ((unsigned)(cv & (BKN - 1)) << 17);
            stage[r] = make_int2((int)pk, __float_as_int(vals[e]));
            gpos[r]  = gshift[b] + r;
        }
    }
    __syncthreads();

#pragma unroll
    for (int k = 0; k < CHUNK / 256; ++k) {
        int i = t + k * 256;
        if (i < n) epk[gpos[i]] = stage[i];   // runs of consecutive addresses
    }
}

// ---------------- within-bucket counting sort by node + CSR offsets ----------------
__global__ void __launch_bounds__(256)
csr_kernel(const int2* __restrict__ epk, const int* __restrict__ boffs,
           int2* __restrict__ epk2, int* __restrict__ node_offs,
           int N, int NB)
{
    __shared__ int  cnt[BKN];
    __shared__ int  sc[BKN];
    __shared__ int  cur[BKN];
    __shared__ int2 stage[STAGE_CAP];   // 32 KB
    const int t = threadIdx.x;
    const int b = blockIdx.x;
    const int s = boffs[b], e = boffs[b + 1];
    const int n = e - s;
    const int node0 = b << BSHIFT;

    if (t < BKN) cnt[t] = 0;
    __syncthreads();
    for (int i = t; i < n; i += 256)
        atomicAdd(&cnt[((unsigned)epk[s + i].x) >> 17], 1);
    __syncthreads();

    if (t < BKN) sc[t] = cnt[t];
    __syncthreads();
    for (int d = 1; d < BKN; d <<= 1) {
        int v = 0;
        if (t < BKN && t >= d) v = sc[t - d];
        __syncthreads();
        if (t < BKN) sc[t] += v;
        __syncthreads();
    }
    if (t < BKN) {
        int excl = sc[t] - cnt[t];
        cur[t] = excl;
        int node = node0 + t;
        if (node < N) node_offs[node] = s + excl;
    }
    if (b == NB - 1 && t == 0) node_offs[N] = e;
    __syncthreads();

    if (n <= STAGE_CAP) {
        for (int i = t; i < n; i += 256) {
            int2 r = epk[s + i];
            int pos = atomicAdd(&cur[((unsigned)r.x) >> 17], 1);
            stage[pos] = r;
        }
        __syncthreads();
        for (int i = t; i < n; i += 256)
            epk2[s + i] = stage[i];           // fully coalesced
    } else {
        for (int i = t; i < n; i += 256) {
            int2 r = epk[s + i];
            int pos = atomicAdd(&cur[((unsigned)r.x) >> 17], 1);
            epk2[s + pos] = r;
        }
    }
}

// ---------------- gather: one wave per destination node, no atomics ----------------
__global__ void __launch_bounds__(256)
gather_kernel(const __hip_bfloat16* __restrict__ hp, const int* __restrict__ node_offs,
              const int2* __restrict__ epk2, float* __restrict__ out, int N)
{
    int wid  = (int)((blockIdx.x * 256u + threadIdx.x) >> 6);   // node id
    int lane = threadIdx.x & 63;                                 // feature id
    if (wid >= N) return;
    int s = node_offs[wid], e = node_offs[wid + 1];
    float acc = 0.f;
    for (int base = s; base < e; base += 64) {
        int n = min(64, e - base);
        int2 m = make_int2(0, 0);
        if (lane < n) m = epk2[base + lane];
        int j = 0;
        for (; j + 4 <= n; j += 4) {
            unsigned r0 = (unsigned)__shfl(m.x, j)     & 0x1FFFFu;
            unsigned r1 = (unsigned)__shfl(m.x, j + 1) & 0x1FFFFu;
            unsigned r2 = (unsigned)__shfl(m.x, j + 2) & 0x1FFFFu;
            unsigned r3 = (unsigned)__shfl(m.x, j + 3) & 0x1FFFFu;
            float v0 = __int_as_float(__shfl(m.y, j));
            float v1 = __int_as_float(__shfl(m.y, j + 1));
            float v2 = __int_as_float(__shfl(m.y, j + 2));
            float v3 = __int_as_float(__shfl(m.y, j + 3));
            float x0 = __bfloat162float(hp[((size_t)r0 << 6) + lane]);
            float x1 = __bfloat162float(hp[((size_t)r1 << 6) + lane]);
            float x2 = __bfloat162float(hp[((size_t)r2 << 6) + lane]);
            float x3 = __bfloat162float(hp[((size_t)r3 << 6) + lane]);
            acc = fmaf(v0, x0, acc);
            acc = fmaf(v1, x1, acc);
            acc = fmaf(v2, x2, acc);
            acc = fmaf(v3, x3, acc);
        }
        for (; j < n; ++j) {
            unsigned r = (unsigned)__shfl(m.x, j) & 0x1FFFFu;
            float    v = __int_as_float(__shfl(m.y, j));
            acc = fmaf(v, __bfloat162float(hp[((size_t)r << 6) + lane]), acc);
        }
    }
    out[(size_t)wid * OU_F + lane] = acc;
}

// ---------------- fallback (atomic scatter) ----------------
__global__ void __launch_bounds__(256)
scatter_kernel(const __hip_bfloat16* __restrict__ hp, const int* __restrict__ row,
               const int* __restrict__ col, const float* __restrict__ vals,
               float* __restrict__ out, int E)
{
    unsigned int gid = blockIdx.x * 256u + threadIdx.x;
    int e = (int)(gid >> 6);
    if (e >= E) return;
    int f = (int)(gid & 63u);
    int r = row[e], c = col[e];
    float m = vals[e] * __bfloat162float(hp[(size_t)r * OU_F + f]);
    __hip_atomic_fetch_add(&out[(size_t)c * OU_F + f], m,
                           __ATOMIC_RELAXED, __HIP_MEMORY_SCOPE_AGENT);
}

extern "C" void kernel_launch(void* const* d_in, const int* in_sizes, int n_in,
                              void* d_out, int out_size, void* d_ws, size_t ws_size,
                              hipStream_t stream)
{
    const float* h    = (const float*)d_in[0];
    const float* W    = (const float*)d_in[1];
    const int*   row  = (const int*)d_in[2];
    const int*   col  = (const int*)d_in[3];
    const float* vals = (const float*)d_in[4];
    float*       out  = (float*)d_out;

    const int N = in_sizes[0] / IN_F;
    const int E = in_sizes[2];
    const int NB = (N + BKN - 1) / BKN;

    char*  ws  = (char*)d_ws;
    size_t off = 0;
    auto alloc = [&](size_t bytes) -> char* {
        char* p = ws + off;
        off = (off + bytes + 255) & ~(size_t)255;
        return p;
    };
    __hip_bfloat16* hp = (__hip_bfloat16*)alloc((size_t)N * OU_F * 2);
    int*   bcnt      = (int*)  alloc((size_t)(NBMAX + 1) * 4);   // [NBMAX] = ticket
    int*   boffs     = (int*)  alloc((size_t)(NBMAX + 1) * 4);
    int*   bcursor   = (int*)  alloc((size_t)NBMAX * 4);
    int*   node_offs = (int*)  alloc((size_t)(N + 1) * 4);
    int2*  epk       = (int2*) alloc((size_t)E * 8);
    int2*  epk2      = (int2*) alloc((size_t)E * 8);
    const bool fits = (off <= ws_size) && (NB <= NBMAX) && (N < 131072);

    const int ntiles = (N + 63) / 64;
    gemm_mfma_kernel<<<512, 512, 0, stream>>>(h, W, hp, bcnt, N, ntiles);

    if (fits) {
        hist_scan_kernel<<<256, 256, 0, stream>>>(col, bcnt, boffs, bcursor, E, NB);
        partition_kernel<<<(E + CHUNK - 1) / CHUNK, 256, 0, stream>>>(
            row, col, vals, bcursor, epk, E, NB);
        csr_kernel<<<NB, 256, 0, stream>>>(epk, boffs, epk2, node_offs, N, NB);
        gather_kernel<<<(N + 3) / 4, 256, 0, stream>>>(hp, node_offs, epk2, out, N);
    } else {
        hipMemsetAsync(d_out, 0, (size_t)out_size * sizeof(float), stream);
        unsigned long long total = (unsigned long long)E * 64ull;
        unsigned int sgrid = (unsigned int)((total + 255ull) / 256ull);
        scatter_kernel<<<sgrid, 256, 0, stream>>>(hp, row, col, vals, out, E);
    }
}

// Round 10
// 90.005 us; speedup vs baseline: 1.1865x; 1.0499x over previous
//
#include <hip/hip_runtime.h>
#include <hip/hip_bf16.h>

#define IN_F 256
#define OU_F 64
#define BKN 128          // nodes per bucket
#define BSHIFT 7
#define NBMAX 512        // max buckets supported
#define CHUNK 4096       // edges per partition block
#define STAGE_CAP 4096   // max records staged in LDS by csr_kernel

typedef __attribute__((ext_vector_type(8))) short short8;
typedef __attribute__((ext_vector_type(4))) float f32x4;

__device__ inline short8 cvt8(float4 a, float4 b)
{
    union { short8 s8; __hip_bfloat162 h2[4]; } u;
    u.h2[0] = __float22bfloat162_rn(make_float2(a.x, a.y));
    u.h2[1] = __float22bfloat162_rn(make_float2(a.z, a.w));
    u.h2[2] = __float22bfloat162_rn(make_float2(b.x, b.y));
    u.h2[3] = __float22bfloat162_rn(make_float2(b.z, b.w));
    return u.s8;
}

// ---------------- GEMM: hp(bf16) = h @ W, B-frags in registers ----------------
// One 64-row tile per block (782 blocks, no grid-stride -> no imbalance).
// 8 waves: wave = (rowgrp 0..3) x (colgrp 0..1). W staged once to LDS then
// pulled into 16 register B-frags; main loop: 16 global A-loads + cvt + 16
// MFMA, no LDS, no barriers.
__global__ void __launch_bounds__(512, 4)
gemm_mfma_kernel(const float* __restrict__ h, const float* __restrict__ W,
                 __hip_bfloat16* __restrict__ hp, int* __restrict__ bcnt, int N)
{
    __shared__ unsigned short Wt[64][264];   // 33792 B, [col][k] bf16
    const int t = threadIdx.x;

    if (blockIdx.x == 0)
        for (int i = t; i <= NBMAX; i += 512) bcnt[i] = 0;

    // stage W (256x64 fp32) -> Wt transposed bf16 (coalesced)
#pragma unroll
    for (int i = 0; i < 16; ++i) {
        int p  = t + i * 512;          // 8192 (col, k-pair) slots
        int c  = p & 63;
        int k0 = (p >> 6) << 1;
        float x = W[(size_t)k0 * OU_F + c];
        float y = W[(size_t)(k0 + 1) * OU_F + c];
        __hip_bfloat162 bb = __float22bfloat162_rn(make_float2(x, y));
        *reinterpret_cast<unsigned*>(&Wt[c][k0]) = *reinterpret_cast<unsigned*>(&bb);
    }
    __syncthreads();

    const int l   = t & 63;
    const int wv  = t >> 6;           // 0..7
    const int cl  = l & 15;
    const int kg  = l >> 4;           // 0..3
    const int rg4 = wv & 3;           // row group within 64-row tile
    const int cg  = wv >> 2;          // col group (32 cols each)

    short8 bfr[2][8];
#pragma unroll
    for (int nt2 = 0; nt2 < 2; ++nt2)
#pragma unroll
        for (int ks = 0; ks < 8; ++ks)
            bfr[nt2][ks] = *reinterpret_cast<const short8*>(
                &Wt[cg * 32 + nt2 * 16 + cl][ks * 32 + kg * 8]);

    const int rbase = blockIdx.x * 64 + rg4 * 16;
    const int r     = rbase + cl;
    const int rld   = min(r, N - 1);
    const float4* hrow = reinterpret_cast<const float4*>(h) + (size_t)rld * (IN_F / 4);

    f32x4 acc0 = (f32x4){0.f, 0.f, 0.f, 0.f};
    f32x4 acc1 = (f32x4){0.f, 0.f, 0.f, 0.f};
#pragma unroll
    for (int ks = 0; ks < 8; ++ks) {
        float4 a0 = hrow[ks * 8 + kg * 2];
        float4 a1 = hrow[ks * 8 + kg * 2 + 1];
        short8 af = cvt8(a0, a1);
        acc0 = __builtin_amdgcn_mfma_f32_16x16x32_bf16(af, bfr[0][ks], acc0, 0, 0, 0);
        acc1 = __builtin_amdgcn_mfma_f32_16x16x32_bf16(af, bfr[1][ks], acc1, 0, 0, 0);
    }

    // D: col = lane&15 (cl), row = kg*4 + reg within the 16-row subtile
#pragma unroll
    for (int rg = 0; rg < 4; ++rg) {
        int rr = rbase + kg * 4 + rg;
        if (rr < N) {
            size_t base = (size_t)rr * OU_F + cg * 32 + cl;
            hp[base]      = __float2bfloat16(acc0[rg]);
            hp[base + 16] = __float2bfloat16(acc1[rg]);
        }
    }
}

// ---------------- hist + scan fused (last-block-done ticket) ----------------
__global__ void __launch_bounds__(256)
hist_scan_kernel(const int* __restrict__ col, int* __restrict__ bcnt,
                 int* __restrict__ boffs, int* __restrict__ bcursor, int E, int NB)
{
    __shared__ int lh[NBMAX];
    __shared__ int s[256];
    __shared__ int isLast;
    const int t = threadIdx.x;

    for (int i = t; i < NB; i += 256) lh[i] = 0;
    __syncthreads();

    const int n4 = E >> 2;
    const int4* c4 = (const int4*)col;
    for (int i = blockIdx.x * 256 + t; i < n4; i += gridDim.x * 256) {
        int4 v = c4[i];
        atomicAdd(&lh[v.x >> BSHIFT], 1);
        atomicAdd(&lh[v.y >> BSHIFT], 1);
        atomicAdd(&lh[v.z >> BSHIFT], 1);
        atomicAdd(&lh[v.w >> BSHIFT], 1);
    }
    if (blockIdx.x == 0)
        for (int e = (n4 << 2) + t; e < E; e += 256)
            atomicAdd(&lh[col[e] >> BSHIFT], 1);
    __syncthreads();

    for (int i = t; i < NB; i += 256)
        if (lh[i]) atomicAdd(&bcnt[i], lh[i]);

    __threadfence();
    if (t == 0) {
        int v = atomicAdd(&bcnt[NBMAX], 1);
        isLast = (v == (int)gridDim.x - 1);
    }
    __syncthreads();
    if (!isLast) return;

    for (int i = t; i < NB; i += 256)
        lh[i] = __hip_atomic_load(&bcnt[i], __ATOMIC_RELAXED, __HIP_MEMORY_SCOPE_AGENT);
    __syncthreads();

    int idx = t * 2;
    int c0 = (idx     < NB) ? lh[idx]     : 0;
    int c1 = (idx + 1 < NB) ? lh[idx + 1] : 0;
    int s0 = c0, s1 = s0 + c1;
    s[t] = s1;
    __syncthreads();
    for (int d = 1; d < 256; d <<= 1) {
        int v = (t >= d) ? s[t - d] : 0;
        __syncthreads();
        s[t] += v;
        __syncthreads();
    }
    int excl = (t > 0) ? s[t - 1] : 0;
    if (idx     < NB) { boffs[idx]     = excl;      bcursor[idx]     = excl;      }
    if (idx + 1 < NB) { boffs[idx + 1] = excl + s0; bcursor[idx + 1] = excl + s0; }
    if (t == 255) boffs[NB] = s[255];
}

// ---------------- partition: counting-sort edges into buckets (512 thr) ----------------
__global__ void __launch_bounds__(512)
partition_kernel(const int* __restrict__ row, const int* __restrict__ col,
                 const float* __restrict__ vals, int* __restrict__ bcursor,
                 int2* __restrict__ epk, int E, int NB)
{
    __shared__ int  hist[NBMAX];
    __shared__ int  X[NBMAX];
    __shared__ int  gshift[NBMAX];
    __shared__ int  s[256];
    __shared__ int2 stage[CHUNK];  // 32 KB
    __shared__ int  gpos[CHUNK];   // 16 KB

    const int t = threadIdx.x;
    const int base = blockIdx.x * CHUNK;
    const int n = min(CHUNK, E - base);

    for (int i = t; i < NBMAX; i += 512) hist[i] = 0;
    __syncthreads();

#pragma unroll
    for (int k = 0; k < CHUNK / 512; ++k) {
        int i = t + k * 512;
        if (i < n) atomicAdd(&hist[col[base + i] >> BSHIFT], 1);
    }
    __syncthreads();

    // 512-entry exclusive scan: threads 0..255 own 2 entries each
    int s0 = 0, s1 = 0;
    if (t < 256) {
        int idx = t * 2;
        s0 = hist[idx];
        s1 = s0 + hist[idx + 1];
        s[t] = s1;
    }
    __syncthreads();
    for (int d = 1; d < 256; d <<= 1) {
        int v = (t >= d && t < 256) ? s[t - d] : 0;
        __syncthreads();
        if (t < 256) s[t] += v;
        __syncthreads();
    }
    if (t < 256) {
        int excl = (t > 0) ? s[t - 1] : 0;
        X[t * 2]     = excl;
        X[t * 2 + 1] = excl + s0;
    }
    __syncthreads();

    for (int i = t; i < NB; i += 512) {
        int hcnt = hist[i];
        int g = hcnt ? atomicAdd(&bcursor[i], hcnt) : 0;
        gshift[i] = g - X[i];
    }
    __syncthreads();

#pragma unroll
    for (int k = 0; k < CHUNK / 512; ++k) {
        int i = t + k * 512;
        if (i < n) {
            int e  = base + i;
            int cv = col[e];
            int b  = cv >> BSHIFT;
            int r  = atomicAdd(&X[b], 1);
            unsigned pk = (unsigned)row[e] | ((unsigned)(cv & (BKN - 1)) << 17);
            stage[r] = make_int2((int)pk, __float_as_int(vals[e]));
            gpos[r]  = gshift[b] + r;
        }
    }
    __syncthreads();

#pragma unroll
    for (int k = 0; k < CHUNK / 512; ++k) {
        int i = t + k * 512;
        if (i < n) epk[gpos[i]] = stage[i];   // runs of consecutive addresses
    }
}

// ---------------- within-bucket counting sort by node + CSR offsets (512 thr) ----------------
__global__ void __launch_bounds__(512)
csr_kernel(const int2* __restrict__ epk, const int* __restrict__ boffs,
           int2* __restrict__ epk2, int* __restrict__ node_offs,
           int N, int NB)
{
    __shared__ int  cnt[BKN];
    __shared__ int  cur[BKN];
    __shared__ int2 stage[STAGE_CAP];   // 32 KB
    const int t = threadIdx.x;
    const int b = blockIdx.x;
    const int s = boffs[b], e = boffs[b + 1];
    const int n = e - s;
    const int node0 = b << BSHIFT;

    if (t < BKN) cnt[t] = 0;
    __syncthreads();
    for (int i = t; i < n; i += 512)
        atomicAdd(&cnt[((unsigned)epk[s + i].x) >> 17], 1);
    __syncthreads();

    // 128-entry exclusive scan in ONE wave: lane owns cnt[2l], cnt[2l+1]
    if (t < 64) {
        int v0 = cnt[2 * t], v1 = cnt[2 * t + 1];
        int p = v0 + v1, sum = p;
#pragma unroll
        for (int d = 1; d < 64; d <<= 1) {
            int u = __shfl_up(sum, d);
            if (t >= d) sum += u;
        }
        int excl = sum - p;
        cur[2 * t]     = excl;
        cur[2 * t + 1] = excl + v0;
        int nd0 = node0 + 2 * t;
        if (nd0 < N)     node_offs[nd0]     = s + excl;
        if (nd0 + 1 < N) node_offs[nd0 + 1] = s + excl + v0;
    }
    if (b == NB - 1 && t == 0) node_offs[N] = e;
    __syncthreads();

    if (n <= STAGE_CAP) {
        for (int i = t; i < n; i += 512) {
            int2 r = epk[s + i];
            int pos = atomicAdd(&cur[((unsigned)r.x) >> 17], 1);
            stage[pos] = r;
        }
        __syncthreads();
        for (int i = t; i < n; i += 512)
            epk2[s + i] = stage[i];           // fully coalesced
    } else {
        for (int i = t; i < n; i += 512) {
            int2 r = epk[s + i];
            int pos = atomicAdd(&cur[((unsigned)r.x) >> 17], 1);
            epk2[s + pos] = r;
        }
    }
}

// ---------------- gather: one wave per destination node, no atomics ----------------
__global__ void __launch_bounds__(256)
gather_kernel(const __hip_bfloat16* __restrict__ hp, const int* __restrict__ node_offs,
              const int2* __restrict__ epk2, float* __restrict__ out, int N)
{
    int wid  = (int)((blockIdx.x * 256u + threadIdx.x) >> 6);   // node id
    int lane = threadIdx.x & 63;                                 // feature id
    if (wid >= N) return;
    int s = node_offs[wid], e = node_offs[wid + 1];
    float acc = 0.f;
    for (int base = s; base < e; base += 64) {
        int n = min(64, e - base);
        int2 m = make_int2(0, 0);
        if (lane < n) m = epk2[base + lane];
        int j = 0;
        for (; j + 4 <= n; j += 4) {
            unsigned r0 = (unsigned)__shfl(m.x, j)     & 0x1FFFFu;
            unsigned r1 = (unsigned)__shfl(m.x, j + 1) & 0x1FFFFu;
            unsigned r2 = (unsigned)__shfl(m.x, j + 2) & 0x1FFFFu;
            unsigned r3 = (unsigned)__shfl(m.x, j + 3) & 0x1FFFFu;
            float v0 = __int_as_float(__shfl(m.y, j));
            float v1 = __int_as_float(__shfl(m.y, j + 1));
            float v2 = __int_as_float(__shfl(m.y, j + 2));
            float v3 = __int_as_float(__shfl(m.y, j + 3));
            float x0 = __bfloat162float(hp[((size_t)r0 << 6) + lane]);
            float x1 = __bfloat162float(hp[((size_t)r1 << 6) + lane]);
            float x2 = __bfloat162float(hp[((size_t)r2 << 6) + lane]);
            float x3 = __bfloat162float(hp[((size_t)r3 << 6) + lane]);
            acc = fmaf(v0, x0, acc);
            acc = fmaf(v1, x1, acc);
            acc = fmaf(v2, x2, acc);
            acc = fmaf(v3, x3, acc);
        }
        for (; j < n; ++j) {
            unsigned r = (unsigned)__shfl(m.x, j) & 0x1FFFFu;
            float    v = __int_as_float(__shfl(m.y, j));
            acc = fmaf(v, __bfloat162float(hp[((size_t)r << 6) + lane]), acc);
        }
    }
    out[(size_t)wid * OU_F + lane] = acc;
}

// ---------------- fallback (atomic scatter) ----------------
__global__ void __launch_bounds__(256)
scatter_kernel(const __hip_bfloat16* __restrict__ hp, const int* __restrict__ row,
               const int* __restrict__ col, const float* __restrict__ vals,
               float* __restrict__ out, int E)
{
    unsigned int gid = blockIdx.x * 256u + threadIdx.x;
    int e = (int)(gid >> 6);
    if (e >= E) return;
    int f = (int)(gid & 63u);
    int r = row[e], c = col[e];
    float m = vals[e] * __bfloat162float(hp[(size_t)r * OU_F + f]);
    __hip_atomic_fetch_add(&out[(size_t)c * OU_F + f], m,
                           __ATOMIC_RELAXED, __HIP_MEMORY_SCOPE_AGENT);
}

extern "C" void kernel_launch(void* const* d_in, const int* in_sizes, int n_in,
                              void* d_out, int out_size, void* d_ws, size_t ws_size,
                              hipStream_t stream)
{
    const float* h    = (const float*)d_in[0];
    const float* W    = (const float*)d_in[1];
    const int*   row  = (const int*)d_in[2];
    const int*   col  = (const int*)d_in[3];
    const float* vals = (const float*)d_in[4];
    float*       out  = (float*)d_out;

    const int N = in_sizes[0] / IN_F;
    const int E = in_sizes[2];
    const int NB = (N + BKN - 1) / BKN;

    char*  ws  = (char*)d_ws;
    size_t off = 0;
    auto alloc = [&](size_t bytes) -> char* {
        char* p = ws + off;
        off = (off + bytes + 255) & ~(size_t)255;
        return p;
    };
    __hip_bfloat16* hp = (__hip_bfloat16*)alloc((size_t)N * OU_F * 2);
    int*   bcnt      = (int*)  alloc((size_t)(NBMAX + 1) * 4);   // [NBMAX] = ticket
    int*   boffs     = (int*)  alloc((size_t)(NBMAX + 1) * 4);
    int*   bcursor   = (int*)  alloc((size_t)NBMAX * 4);
    int*   node_offs = (int*)  alloc((size_t)(N + 1) * 4);
    int2*  epk       = (int2*) alloc((size_t)E * 8);
    int2*  epk2      = (int2*) alloc((size_t)E * 8);
    const bool fits = (off <= ws_size) && (NB <= NBMAX) && (N < 131072);

    const int ntiles = (N + 63) / 64;
    gemm_mfma_kernel<<<ntiles, 512, 0, stream>>>(h, W, hp, bcnt, N);

    if (fits) {
        hist_scan_kernel<<<256, 256, 0, stream>>>(col, bcnt, boffs, bcursor, E, NB);
        partition_kernel<<<(E + CHUNK - 1) / CHUNK, 512, 0, stream>>>(
            row, col, vals, bcursor, epk, E, NB);
        csr_kernel<<<NB, 512, 0, stream>>>(epk, boffs, epk2, node_offs, N, NB);
        gather_kernel<<<(N + 3) / 4, 256, 0, stream>>>(hp, node_offs, epk2, out, N);
    } else {
        hipMemsetAsync(d_out, 0, (size_t)out_size * sizeof(float), stream);
        unsigned long long total = (unsigned long long)E * 64ull;
        unsigned int sgrid = (unsigned int)((total + 255ull) / 256ull);
        scatter_kernel<<<sgrid, 256, 0, stream>>>(hp, row, col, vals, out, E);
    }
}